// Round 3
// baseline (3508.819 us; speedup 1.0000x reference)
//
#include <hip/hip_runtime.h>

#define BB 16
#define CC 16
#define HH 384
#define WW 384
#define HWSZ (HH*WW)
#define CHW (CC*HWSZ)
#define KS 11

#define F_HSEGS 32
#define F_BANDH (HH/F_HSEGS)   // 12 rows per band

// ---------------------------------------------------------------------------
// K1: per-(b,h) row — softmax over C, then 11-tap conv along W (center tap 0).
// Writes t = ConvW(softmax(x)).  (first iteration only)
// ---------------------------------------------------------------------------
__global__ __launch_bounds__(WW) void k_softmax_convw(
    const float* __restrict__ xin, float* __restrict__ t,
    const float* __restrict__ spacings, const float* __restrict__ invtheta)
{
    const int h = blockIdx.x;
    const int b = blockIdx.y;
    const int w = threadIdx.x;
    __shared__ float p[CC][WW];

    const float* xb = xin + (size_t)b * CHW + (size_t)h * WW + w;
    float v[CC];
#pragma unroll
    for (int c = 0; c < CC; ++c) v[c] = xb[(size_t)c * HWSZ];

    float m = v[0];
#pragma unroll
    for (int c = 1; c < CC; ++c) m = fmaxf(m, v[c]);
    float s = 0.f;
#pragma unroll
    for (int c = 0; c < CC; ++c) { v[c] = __expf(v[c] - m); s += v[c]; }
    const float inv = 1.0f / s;
#pragma unroll
    for (int c = 0; c < CC; ++c) p[c][w] = v[c] * inv;

    const float sc = spacings[b * 2 + 1] * invtheta[1];  // W axis = spatial axis 1
    float kw[KS];
#pragma unroll
    for (int j = 0; j < KS; ++j) { float d = sc * (float)(j - 5); kw[j] = __expf(-0.5f * d * d); }
    kw[5] = 0.f;

    __syncthreads();

    float* tb = t + (size_t)b * CHW + (size_t)h * WW + w;
#pragma unroll
    for (int c = 0; c < CC; ++c) {
        float acc = 0.f;
#pragma unroll
        for (int j = 0; j < KS; ++j) {
            if (j == 5) continue;
            const int ww = w + j - 5;
            const float pv = (ww >= 0 && ww < WW) ? p[c][ww] : 0.f;
            acc = fmaf(kw[j], pv, acc);
        }
        tb[(size_t)c * HWSZ] = acc;
    }
}

// ---------------------------------------------------------------------------
// F: fused iteration  t_{n+1} = ConvW(softmax(x0 + sw*ConvH(t_n))).
// Block = (b, 12-row band), 384 threads (one per w).
// Phase1: ConvH via wave-uniform-row global loads (L2 catches 11x row reuse)
//         + update + softmax in registers -> LDS row (double buffered).
// Phase2: ConvW from LDS -> t_out.  One barrier per row.
// ---------------------------------------------------------------------------
__global__ __launch_bounds__(WW) void k_fused_iter(
    const float* __restrict__ tin, const float* __restrict__ x0,
    float* __restrict__ tout,
    const float* __restrict__ spacings, const float* __restrict__ invtheta,
    const float* __restrict__ swp)
{
    const int b  = blockIdx.y;
    const int h0 = blockIdx.x * F_BANDH;
    const int w  = threadIdx.x;

    __shared__ float p[2][CC][WW];   // 48 KB, double buffered

    const float sw  = swp[0];
    const float sch = spacings[b * 2 + 0] * invtheta[0];  // H axis
    const float scw = spacings[b * 2 + 1] * invtheta[1];  // W axis
    float kh[KS], kw[KS];
#pragma unroll
    for (int j = 0; j < KS; ++j) {
        float dh = sch * (float)(j - 5); kh[j] = __expf(-0.5f * dh * dh);
        float dw = scw * (float)(j - 5); kw[j] = __expf(-0.5f * dw * dw);
    }
    kh[5] = 0.f; kw[5] = 0.f;

    const float* tb = tin  + (size_t)b * CHW + w;
    const float* ub = x0   + (size_t)b * CHW + w;
    float*       ob = tout + (size_t)b * CHW + w;

    int buf = 0;
    for (int h = h0; h < h0 + F_BANDH; ++h) {
        // ---- phase 1: x = x0 + sw*ConvH(t); softmax over C ----
        float v[CC];
#pragma unroll
        for (int c = 0; c < CC; ++c) {
            const float* tc = tb + (size_t)c * HWSZ;
            float acc = 0.f;
#pragma unroll
            for (int j = 0; j < KS; ++j) {
                if (j == 5) continue;
                const int r = h + j - 5;
                if ((unsigned)r < HH) acc = fmaf(kh[j], tc[(size_t)r * WW], acc);
            }
            v[c] = fmaf(sw, acc, ub[(size_t)c * HWSZ + (size_t)h * WW]);
        }
        float m = v[0];
#pragma unroll
        for (int c = 1; c < CC; ++c) m = fmaxf(m, v[c]);
        float s = 0.f;
#pragma unroll
        for (int c = 0; c < CC; ++c) { v[c] = __expf(v[c] - m); s += v[c]; }
        const float inv = 1.0f / s;
#pragma unroll
        for (int c = 0; c < CC; ++c) p[buf][c][w] = v[c] * inv;

        __syncthreads();

        // ---- phase 2: t' = ConvW(p) ----
#pragma unroll
        for (int c = 0; c < CC; ++c) {
            float acc = 0.f;
#pragma unroll
            for (int j = 0; j < KS; ++j) {
                if (j == 5) continue;
                const int ww = w + j - 5;
                const float pv = (ww >= 0 && ww < WW) ? p[buf][c][ww] : 0.f;
                acc = fmaf(kw[j], pv, acc);
            }
            ob[(size_t)c * HWSZ + (size_t)h * WW] = acc;
        }
        buf ^= 1;
        // safe: next overwrite of this buf is 2 rows away, past the next barrier
    }
}

// ---------------------------------------------------------------------------
// G: final  out = log_softmax(x0 + sw*ConvH(t4)).  No LDS, no barriers.
// ---------------------------------------------------------------------------
__global__ __launch_bounds__(WW) void k_final(
    const float* __restrict__ tin, const float* __restrict__ x0,
    float* __restrict__ out,
    const float* __restrict__ spacings, const float* __restrict__ invtheta,
    const float* __restrict__ swp)
{
    const int b  = blockIdx.y;
    const int h0 = blockIdx.x * F_BANDH;
    const int w  = threadIdx.x;

    const float sw  = swp[0];
    const float sch = spacings[b * 2 + 0] * invtheta[0];
    float kh[KS];
#pragma unroll
    for (int j = 0; j < KS; ++j) { float d = sch * (float)(j - 5); kh[j] = __expf(-0.5f * d * d); }
    kh[5] = 0.f;

    const float* tb = tin + (size_t)b * CHW + w;
    const float* ub = x0  + (size_t)b * CHW + w;
    float*       oo = out + (size_t)b * CHW + w;

    for (int h = h0; h < h0 + F_BANDH; ++h) {
        float v[CC];
#pragma unroll
        for (int c = 0; c < CC; ++c) {
            const float* tc = tb + (size_t)c * HWSZ;
            float acc = 0.f;
#pragma unroll
            for (int j = 0; j < KS; ++j) {
                if (j == 5) continue;
                const int r = h + j - 5;
                if ((unsigned)r < HH) acc = fmaf(kh[j], tc[(size_t)r * WW], acc);
            }
            v[c] = fmaf(sw, acc, ub[(size_t)c * HWSZ + (size_t)h * WW]);
        }
        float m = v[0];
#pragma unroll
        for (int c = 1; c < CC; ++c) m = fmaxf(m, v[c]);
        float s = 0.f;
#pragma unroll
        for (int c = 0; c < CC; ++c) s += __expf(v[c] - m);
        const float l = m + __logf(s);
#pragma unroll
        for (int c = 0; c < CC; ++c)
            oo[(size_t)c * HWSZ + (size_t)h * WW] = v[c] - l;
    }
}

// ---------------------------------------------------------------------------
extern "C" void kernel_launch(void* const* d_in, const int* in_sizes, int n_in,
                              void* d_out, int out_size, void* d_ws, size_t ws_size,
                              hipStream_t stream)
{
    const float* x0   = (const float*)d_in[0];  // (B,C,H,W) unaries
    const float* spac = (const float*)d_in[1];  // (B,2)
    const float* sw   = (const float*)d_in[2];  // scalar
    const float* it   = (const float*)d_in[3];  // (2,)

    float* t_ws  = (float*)d_ws;   // t ping buffer
    float* t_out = (float*)d_out;  // t pong buffer / final output

    dim3 g1(HH, BB);
    dim3 gf(F_HSEGS, BB);          // 512 blocks

    // t0 = ConvW(softmax(x0))
    k_softmax_convw<<<g1, dim3(WW), 0, stream>>>(x0, t_ws, spac, it);
    // t1..t4 via fused iterations, ping-ponging ws <-> out
    k_fused_iter<<<gf, dim3(WW), 0, stream>>>(t_ws,  x0, t_out, spac, it, sw);
    k_fused_iter<<<gf, dim3(WW), 0, stream>>>(t_out, x0, t_ws,  spac, it, sw);
    k_fused_iter<<<gf, dim3(WW), 0, stream>>>(t_ws,  x0, t_out, spac, it, sw);
    k_fused_iter<<<gf, dim3(WW), 0, stream>>>(t_out, x0, t_ws,  spac, it, sw);
    // out = log_softmax(x0 + sw*ConvH(t4))
    k_final<<<gf, dim3(WW), 0, stream>>>(t_ws, x0, t_out, spac, it, sw);
}

// Round 4
// 486.146 us; speedup vs baseline: 7.2176x; 7.2176x over previous
//
#include <hip/hip_runtime.h>

#define BB 16
#define CC 16
#define HH 384
#define WW 384
#define HWSZ (HH*WW)
#define CHW (CC*HWSZ)
#define NPIX (BB*CHW)
#define KS 11

#define K2_THREADS 256
#define K2_HSEGS 24
#define K2_SEGH (HH/K2_HSEGS)    // 16 rows per segment
#define W8 (WW/8)                // 48 ushort8-columns per row
#define ROWU4 (WW/8)             // row stride in uint4 units (bf16)

typedef unsigned short ushortT;

// ---- bf16 helpers (raw-bit, RNE) -----------------------------------------
__device__ __forceinline__ float bf2f(ushortT h) {
    union { unsigned u; float f; } c; c.u = ((unsigned)h) << 16; return c.f;
}
__device__ __forceinline__ ushortT f2bf(float f) {
    union { float f; unsigned u; } c; c.f = f;
    unsigned r = c.u + 0x7FFFu + ((c.u >> 16) & 1u);
    return (ushortT)(r >> 16);
}
__device__ __forceinline__ void unpk2(unsigned u, float& lo, float& hi) {
    union { unsigned u; float f; } a, b;
    a.u = u << 16; b.u = u & 0xFFFF0000u;
    lo = a.f; hi = b.f;
}
__device__ __forceinline__ unsigned pk2(float lo, float hi) {
    return ((unsigned)f2bf(hi) << 16) | (unsigned)f2bf(lo);
}

// ---------------------------------------------------------------------------
// k_cvt: x0 (f32) -> x0b (bf16), 8 elems/thread.
// ---------------------------------------------------------------------------
__global__ __launch_bounds__(256) void k_cvt(const float* __restrict__ x0,
                                             ushortT* __restrict__ x0b)
{
    const int i = blockIdx.x * 256 + threadIdx.x;
    if (i >= NPIX / 8) return;
    const float4 a = ((const float4*)x0)[2 * i];
    const float4 b = ((const float4*)x0)[2 * i + 1];
    uint4 o;
    o.x = pk2(a.x, a.y); o.y = pk2(a.z, a.w);
    o.z = pk2(b.x, b.y); o.w = pk2(b.z, b.w);
    ((uint4*)x0b)[i] = o;
}

// ---------------------------------------------------------------------------
// K1: per-(b,h) row — softmax over C then 11-tap ConvW (center 0). bf16 in/out.
// ---------------------------------------------------------------------------
__global__ __launch_bounds__(WW) void k_smax_convw(
    const ushortT* __restrict__ xin, ushortT* __restrict__ t,
    const float* __restrict__ spacings, const float* __restrict__ invtheta)
{
    const int h = blockIdx.x;
    const int b = blockIdx.y;
    const int w = threadIdx.x;
    __shared__ float p[CC][WW];

    const ushortT* xb = xin + (size_t)b * CHW + (size_t)h * WW + w;
    float v[CC];
#pragma unroll
    for (int c = 0; c < CC; ++c) v[c] = bf2f(xb[(size_t)c * HWSZ]);

    float m = v[0];
#pragma unroll
    for (int c = 1; c < CC; ++c) m = fmaxf(m, v[c]);
    float s = 0.f;
#pragma unroll
    for (int c = 0; c < CC; ++c) { v[c] = __expf(v[c] - m); s += v[c]; }
    const float inv = 1.0f / s;
#pragma unroll
    for (int c = 0; c < CC; ++c) p[c][w] = v[c] * inv;

    const float sc = spacings[b * 2 + 1] * invtheta[1];  // W axis = spatial axis 1
    float kw[KS];
#pragma unroll
    for (int j = 0; j < KS; ++j) { float d = sc * (float)(j - 5); kw[j] = __expf(-0.5f * d * d); }
    kw[5] = 0.f;

    __syncthreads();

    ushortT* tb = t + (size_t)b * CHW + (size_t)h * WW + w;
#pragma unroll
    for (int c = 0; c < CC; ++c) {
        float acc = 0.f;
#pragma unroll
        for (int j = 0; j < KS; ++j) {
            if (j == 5) continue;
            const int ww = w + j - 5;
            const float pv = (ww >= 0 && ww < WW) ? p[c][ww] : 0.f;
            acc = fmaf(kw[j], pv, acc);
        }
        tb[(size_t)c * HWSZ] = f2bf(acc);
    }
}

// ---------------------------------------------------------------------------
// K2: ConvH (rolling bf16x8 window) + x = x0b + sw*conv.  bf16 in/out.
// Thread owns 8 adjacent columns (one uint4 of packed bf16).
// ---------------------------------------------------------------------------
__global__ __launch_bounds__(K2_THREADS) void k_convh_add(
    const ushortT* __restrict__ t, const ushortT* __restrict__ x0b,
    ushortT* __restrict__ xout,
    const float* __restrict__ spacings, const float* __restrict__ invtheta,
    const float* __restrict__ swp)
{
    const int colIdx = blockIdx.x * K2_THREADS + threadIdx.x;  // [0, CC*W8)
    const int c  = colIdx / W8;
    const int w8 = colIdx - c * W8;
    const int b  = blockIdx.z;
    const int h0 = blockIdx.y * K2_SEGH;

    const float sw = swp[0];
    const float sc = spacings[b * 2 + 0] * invtheta[0];  // H axis = spatial axis 0
    float kh[KS];
#pragma unroll
    for (int j = 0; j < KS; ++j) { float d = sc * (float)(j - 5); kh[j] = __expf(-0.5f * d * d); }
    kh[5] = 0.f;

    const size_t base = (size_t)(b * CC + c) * HWSZ + (size_t)w8 * 8;  // ushort idx
    const uint4* tb = (const uint4*)(t    + base);
    const uint4* ub = (const uint4*)(x0b  + base);
    uint4*       ob = (uint4*)      (xout + base);

    const uint4 z4 = make_uint4(0u, 0u, 0u, 0u);
    uint4 win[KS];
#pragma unroll
    for (int j = 0; j < KS; ++j) {
        const int r = h0 + j - 5;
        win[j] = ((unsigned)r < HH) ? tb[(size_t)r * ROWU4] : z4;
    }

#pragma unroll 4
    for (int h = h0; h < h0 + K2_SEGH; ++h) {
        const int nr = h + 6;
        const uint4 nt = (nr < HH) ? tb[(size_t)nr * ROWU4] : z4;   // prefetch
        const uint4 u  = ub[(size_t)h * ROWU4];

        float acc[8];
#pragma unroll
        for (int k = 0; k < 8; ++k) acc[k] = 0.f;
#pragma unroll
        for (int j = 0; j < KS; ++j) {
            if (j == 5) continue;
            float e0, e1, e2, e3, e4, e5, e6, e7;
            unpk2(win[j].x, e0, e1); unpk2(win[j].y, e2, e3);
            unpk2(win[j].z, e4, e5); unpk2(win[j].w, e6, e7);
            const float kj = kh[j];
            acc[0] = fmaf(kj, e0, acc[0]); acc[1] = fmaf(kj, e1, acc[1]);
            acc[2] = fmaf(kj, e2, acc[2]); acc[3] = fmaf(kj, e3, acc[3]);
            acc[4] = fmaf(kj, e4, acc[4]); acc[5] = fmaf(kj, e5, acc[5]);
            acc[6] = fmaf(kj, e6, acc[6]); acc[7] = fmaf(kj, e7, acc[7]);
        }
        float u0, u1, u2, u3, u4, u5, u6, u7;
        unpk2(u.x, u0, u1); unpk2(u.y, u2, u3);
        unpk2(u.z, u4, u5); unpk2(u.w, u6, u7);
        uint4 o;
        o.x = pk2(fmaf(sw, acc[0], u0), fmaf(sw, acc[1], u1));
        o.y = pk2(fmaf(sw, acc[2], u2), fmaf(sw, acc[3], u3));
        o.z = pk2(fmaf(sw, acc[4], u4), fmaf(sw, acc[5], u5));
        o.w = pk2(fmaf(sw, acc[6], u6), fmaf(sw, acc[7], u7));
        ob[(size_t)h * ROWU4] = o;

#pragma unroll
        for (int j = 0; j < KS - 1; ++j) win[j] = win[j + 1];
        win[KS - 1] = nt;
    }
}

// ---------------------------------------------------------------------------
// K3: log_softmax over C, bf16 in -> f32 out.  4 pixels per thread.
// ---------------------------------------------------------------------------
__global__ __launch_bounds__(256) void k_final(
    const ushortT* __restrict__ xf, float* __restrict__ out)
{
    const int p4 = blockIdx.x * 256 + threadIdx.x;
    if (p4 >= (BB * HWSZ) / 4) return;
    const int b  = p4 / (HWSZ / 4);
    const int r4 = p4 - b * (HWSZ / 4);
    const size_t base = (size_t)b * CHW + (size_t)r4 * 4;

    float v[CC][4];
#pragma unroll
    for (int c = 0; c < CC; ++c) {
        const uint2 u = *(const uint2*)(xf + base + (size_t)c * HWSZ);
        unpk2(u.x, v[c][0], v[c][1]);
        unpk2(u.y, v[c][2], v[c][3]);
    }
#pragma unroll
    for (int k = 0; k < 4; ++k) {
        float m = v[0][k];
#pragma unroll
        for (int c = 1; c < CC; ++c) m = fmaxf(m, v[c][k]);
        float s = 0.f;
#pragma unroll
        for (int c = 0; c < CC; ++c) s += __expf(v[c][k] - m);
        const float l = m + __logf(s);
#pragma unroll
        for (int c = 0; c < CC; ++c) v[c][k] -= l;
    }
#pragma unroll
    for (int c = 0; c < CC; ++c) {
        float4 o = make_float4(v[c][0], v[c][1], v[c][2], v[c][3]);
        *(float4*)(out + base + (size_t)c * HWSZ) = o;
    }
}

// ---------------------------------------------------------------------------
extern "C" void kernel_launch(void* const* d_in, const int* in_sizes, int n_in,
                              void* d_out, int out_size, void* d_ws, size_t ws_size,
                              hipStream_t stream)
{
    const float* x0   = (const float*)d_in[0];  // (B,C,H,W) unaries f32
    const float* spac = (const float*)d_in[1];  // (B,2)
    const float* sw   = (const float*)d_in[2];  // scalar
    const float* it   = (const float*)d_in[3];  // (2,)

    ushortT* x0b = (ushortT*)d_ws;        // bf16 copy of x0 (75.5 MB)
    ushortT* t   = x0b + (size_t)NPIX;    // bf16 smoothed probs  (75.5 MB)
    ushortT* xb  = (ushortT*)d_out;       // bf16 evolving x (first half of d_out)
    float*   out = (float*)d_out;         // final f32 output

    k_cvt<<<(NPIX / 8 + 255) / 256, 256, 0, stream>>>(x0, x0b);

    dim3 g1(HH, BB);
    dim3 g2(CC * W8 / K2_THREADS, K2_HSEGS, BB);   // (3, 24, 16)

    for (int n = 0; n < 5; ++n) {
        k_smax_convw<<<g1, dim3(WW), 0, stream>>>(n == 0 ? x0b : xb, t, spac, it);
        // last iteration writes x5 over x0b (element-wise, same-thread RAW only — safe);
        // x0b is regenerated by k_cvt on every launch, so replay-deterministic.
        k_convh_add<<<g2, dim3(K2_THREADS), 0, stream>>>(
            t, x0b, (n == 4) ? x0b : xb, spac, it, sw);
    }
    const int np4 = (BB * HWSZ) / 4;
    k_final<<<(np4 + 255) / 256, 256, 0, stream>>>(x0b, out);
}